// Round 14
// baseline (115.447 us; speedup 1.0000x reference)
//
#include <hip/hip_runtime.h>
#include <stdint.h>

// Problem constants (fixed by reference setup_inputs)
#define CIN   256
#define COUT  256
#define Hdim  56
#define Wdim  56
#define HW    3136        // 56*56
#define BATCH 32
#define NPIX  100352      // 32*3136
#define KREP  589824      // 256*256*9, stride between weight replicas
#define TAPS  9
#define WORDS 8           // 8 x uint32 = 256 channel bits

// ws layout (bytes). First 3,286,016 B = R7-proven footprint (fallback path).
// W8 (expanded int8 weights, stream-contiguous layout) appended past it.
#define OFF_WBT   0         // 9*2*256*8 ushorts = 73728
#define OFF_SA    73728     // 256*4 = 1024
#define OFF_XBITS 74752     // 100352*8*4 = 3211264
#define OFF_W8    3286016   // 8 cg * 9 t * 8 c * 1024 B = 589824
#define WS_NEED   (OFF_W8 + 589824)

#define CGBYTES   73728     // W8 bytes per 32-co group (9*8*1024)

typedef int int4v  __attribute__((ext_vector_type(4)));
typedef int int16v __attribute__((ext_vector_type(16)));

// 4 sign bits -> 4 int8 lanes of {-1,+1}. Byte-borrow-proof:
// (0x81 - 2b) ^ 0x80 = {0x01, 0xFF} per byte, no cross-byte borrow.
__device__ __forceinline__ uint32_t nib2pm1(uint32_t n) {
    const uint32_t mask = (n * 0x204081u) & 0x01010101u;
    return (0x81818181u - (mask << 1)) ^ 0x80808080u;
}

__device__ __forceinline__ int4v expand_pm1(uint32_t us) {
    int4v r;
    r.x = (int)nib2pm1(us & 15u);
    r.y = (int)nib2pm1((us >> 4) & 15u);
    r.z = (int)nib2pm1((us >> 8) & 15u);
    r.w = (int)nib2pm1((us >> 12) & 15u);
    return r;
}

__device__ __forceinline__ uint32_t ext16(const uint4 v, int c) {
    uint32_t comp = (c < 4) ? ((c < 2) ? v.x : v.y) : ((c < 6) ? v.z : v.w);
    return (c & 1) ? (comp >> 16) : (comp & 0xFFFFu);
}

// ---------------------------------------------------------------------------
// P1: real_w = sum_k RV[k]*W[k]; sa[co] = mean|real_w| * alpha[co];
//     wbT bit-pack (fallback) and W8 expanded int8 B-fragments in the
//     stream-contiguous layout: byte = (co>>5)*73728 + (t*8+c)*1024
//     + g*512 + (co&31)*16. Verified R11/R13.
// ---------------------------------------------------------------------------
__global__ __launch_bounds__(256) void prep_w_kernel(
    const float* __restrict__ wts, const float* __restrict__ RV,
    const float* __restrict__ alpha, unsigned short* __restrict__ wbT,
    float* __restrict__ sa, uint4* __restrict__ w8, int do_w8)
{
    __shared__ uint32_t bits[TAPS * WORDS];   // bits[tap*8 + (ci>>5)]
    __shared__ float    red[256];

    const int co = blockIdx.x;
    const int t  = threadIdx.x;

    if (t < TAPS * WORDS) bits[t] = 0u;
    __syncthreads();

    const float r0 = RV[0], r1 = RV[1], r2 = RV[2], r3 = RV[3];
    const float* base = wts + (size_t)co * 2304;

    float acc = 0.f;
#pragma unroll
    for (int j = 0; j < 9; ++j) {
        const int e = j * 256 + t;              // e = ci*9 + tap
        const float w0 = base[e];
        const float w1 = base[e + KREP];
        const float w2 = base[e + 2 * KREP];
        const float w3 = base[e + 3 * KREP];
        const float rw = r0 * w0 + r1 * w1 + r2 * w2 + r3 * w3;
        acc += fabsf(rw);
        const int ci  = e / 9;
        const int tap = e - ci * 9;
        if (rw < 0.f)
            atomicOr(&bits[tap * WORDS + (ci >> 5)], 1u << (ci & 31));
    }
    red[t] = acc;
    __syncthreads();

    for (int s = 128; s > 0; s >>= 1) {
        if (t < s) red[t] += red[t + s];
        __syncthreads();
    }

    if (t == 0) sa[co] = (red[0] * (1.0f / 2304.0f)) * alpha[co];

    if (t < 144) {                       // wbT: (tap, g, c) — R7-verified
        const int tap = t >> 4;
        const int r   = t & 15;
        const int g   = r >> 3;
        const int c   = r & 7;
        const uint32_t v = (bits[tap * 8 + c] >> (g * 16)) & 0xFFFFu;
        wbT[(((tap * 2 + g) * 256 + co) << 3) + c] = (unsigned short)v;
    }
    if (do_w8 && t < 144) {              // W8 stream layout: (tap, q=2c+g)
        const int tap = t >> 4;
        const int q   = t & 15;
        const int c   = q >> 1;
        const int g   = q & 1;
        const uint32_t v = (bits[tap * 8 + c] >> (g * 16)) & 0xFFFFu;
        uint4 e;
        e.x = nib2pm1(v & 15u);
        e.y = nib2pm1((v >> 4) & 15u);
        e.z = nib2pm1((v >> 8) & 15u);
        e.w = nib2pm1((v >> 12) & 15u);
        // uint4 index: cg*4608 + (tap*8+c)*64 + g*32 + (co&31)
        w8[(co >> 5) * 4608 + (tap * 8 + c) * 64 + g * 32 + (co & 31)] = e;
    }
}

// ---------------------------------------------------------------------------
// P2: binarize+pack x (unpadded [B][56][56][8]) — unchanged, verified R1.
// ---------------------------------------------------------------------------
__global__ __launch_bounds__(256) void pack_x_kernel(
    const float* __restrict__ x, uint32_t* __restrict__ xbits)
{
    const int p  = blockIdx.x * 256 + threadIdx.x;   // pixel id < NPIX
    const int b  = p / HW;
    const int hw = p - b * HW;
    const float* xp = x + (size_t)b * CIN * HW + hw;

    uint32_t wv[WORDS];
#pragma unroll
    for (int j = 0; j < WORDS; ++j) {
        uint32_t m = 0;
#pragma unroll
        for (int bit = 0; bit < 32; ++bit) {
            const float v = xp[(size_t)(j * 32 + bit) * HW];
            m |= (__float_as_uint(v) >> 31) << bit;
        }
        wv[j] = m;
    }
    uint4* dst = (uint4*)(xbits + (size_t)p * WORDS);
    dst[0] = make_uint4(wv[0], wv[1], wv[2], wv[3]);
    dst[1] = make_uint4(wv[4], wv[5], wv[6], wv[7]);
}

// ---------------------------------------------------------------------------
// C (primary): implicit-GEMM XNOR conv, 112-px M-tile, 4-N-frag waves.
// 256-thr blocks = 4 waves (2mg x 2ng); each wave: 2 M-frags x 4 N-frags
// (128 co) -> 8 MFMAs per A-read-pair. A LDS traffic HALVES vs R13 (the
// R13 diagnosis: A-path LDS bandwidth is the wall). B: 2-deep x 4-stream
// asm window, counted vmcnt(4) (R13-proven mechanism + drain).
// ---------------------------------------------------------------------------
__global__ __launch_bounds__(256, 2) void conv_mfma_w8_kernel(
    const uint32_t* __restrict__ xbits, const uint8_t* __restrict__ w8,
    const float* __restrict__ sa_g, float* __restrict__ out)
{
    __shared__ __align__(16) int xt[232 * 64];  // 4 rows x 58 cols x 256B

    const int tid  = threadIdx.x;
    const int lane = tid & 63;
    const int half = lane >> 5;
    const int l31  = lane & 31;
    const int wid  = tid >> 6;       // 0..3
    const int mg   = wid >> 1;       // M-group 0..1
    const int ng   = wid & 1;        // N-group 0..1 (128 co each)

    const int blk = blockIdx.x;
    const int b   = blk / 28;
    const int T   = blk - b * 28;
    const int p0  = T * 112;
    const int h0  = 2 * T;           // first output row (aligned)

    // ---- stage + expand x tile (rows h0-1 .. h0+2, cols -1..56, pad = 0)
    {
        const uint32_t* xb = xbits + (size_t)b * (HW * WORDS);
        for (int u = tid; u < 232 * 32; u += 256) {   // b64 units
            const int cell = u >> 5, p = u & 31;
            const int row = cell / 58;                // 0..3
            const int col = cell - row * 58;          // 0..57
            const int hh = h0 - 1 + row, ww = col - 1;
            const bool ok = (hh >= 0) && (hh < Hdim) && (ww >= 0) && (ww < Wdim);
            uint32_t byteval = 0;
            if (ok)
                byteval = (xb[((hh * 56 + ww) << 3) + (p >> 2)] >> ((p & 3) * 8)) & 0xFFu;
            uint32_t d0 = nib2pm1(byteval & 15u);
            uint32_t d1 = nib2pm1(byteval >> 4);
            if (!ok) { d0 = 0u; d1 = 0u; }            // pad contributes 0
            const int f   = (col + 2 * row) & 15;
            const int idx = cell * 64 + (((p >> 1) ^ f) << 2) + ((p & 1) << 1);
            *reinterpret_cast<uint2*>(&xt[idx]) = make_uint2(d0, d1);
        }
    }
    __syncthreads();

    // ---- per-lane geometry (R9-verified)
    const int m0  = mg * 64 + l31;            // 0..95   (always valid < 112)
    const int m1  = m0 + 32;                  // 32..127 (invalid >= 112)
    const int m1c = (m1 < 112) ? m1 : 111;    // clamp for addressing only
    const int rb0 = m0 / 56,  w_0 = m0 - rb0 * 56;
    const int rb1 = m1c / 56, w_1 = m1c - rb1 * 56;

    // 4 co streams: co_s = ng*128 + s*32 + l31  (cg = ng*4+s)
    const int cob = ng * 128 + l31;
    const float s0 = sa_g[cob], s1 = sa_g[cob + 32],
                s2 = sa_g[cob + 64], s3 = sa_g[cob + 96];

    // B stream bases: lane*16 folds (half, co31); k*1024 walks the stream.
    const uint8_t* sb0 = w8 + (size_t)(ng * 4 + 0) * CGBYTES + (lane << 4);
    const uint8_t* sb1 = sb0 + CGBYTES;
    const uint8_t* sb2 = sb1 + CGBYTES;
    const uint8_t* sb3 = sb2 + CGBYTES;

    int16v ac00 = {0,0,0,0,0,0,0,0,0,0,0,0,0,0,0,0};
    int16v ac01 = {0,0,0,0,0,0,0,0,0,0,0,0,0,0,0,0};
    int16v ac02 = {0,0,0,0,0,0,0,0,0,0,0,0,0,0,0,0};
    int16v ac03 = {0,0,0,0,0,0,0,0,0,0,0,0,0,0,0,0};
    int16v ac10 = {0,0,0,0,0,0,0,0,0,0,0,0,0,0,0,0};
    int16v ac11 = {0,0,0,0,0,0,0,0,0,0,0,0,0,0,0,0};
    int16v ac12 = {0,0,0,0,0,0,0,0,0,0,0,0,0,0,0,0};
    int16v ac13 = {0,0,0,0,0,0,0,0,0,0,0,0,0,0,0,0};

    // B window: 2 slots x 4 streams
    int4v B00, B01, B02, B03, B10, B11, B12, B13;

#define ISSUE(DST, BASE, OFFLIT)                                             \
    asm volatile("global_load_dwordx4 %0, %1, off offset:" OFFLIT           \
                 : "=&v"(DST) : "v"(BASE))

    // prologue: slot0 <- k=0, slot1 <- k=1  (8 loads in flight)
    ISSUE(B00, sb0, "0");    ISSUE(B01, sb1, "0");
    ISSUE(B02, sb2, "0");    ISSUE(B03, sb3, "0");
    ISSUE(B10, sb0, "1024"); ISSUE(B11, sb1, "1024");
    ISSUE(B12, sb2, "1024"); ISSUE(B13, sb3, "1024");

    // STEP CC: consume slot CC&1, do 8 MFMAs, refill slot with k=t*8+CC+2.
#define STEP(CC, Wa, Wb, Wc, Wd, PA, PB, PC, PD, OFFLIT)                     \
    {                                                                        \
        asm volatile("s_waitcnt vmcnt(4)"                                    \
                     : "+v"(Wa), "+v"(Wb), "+v"(Wc), "+v"(Wd));              \
        __builtin_amdgcn_sched_barrier(0x3F7); /* MFMA may not hoist */      \
        const int g0 = ((((CC) << 1) | half) ^ f0) << 2;                     \
        const int g1 = ((((CC) << 1) | half) ^ f1) << 2;                     \
        const int4v av0 = *(const int4v*)&xt[cb0 + g0];                      \
        const int4v av1 = *(const int4v*)&xt[cb1 + g1];                      \
        ac00 = __builtin_amdgcn_mfma_i32_32x32x32_i8(av0, Wa, ac00, 0, 0, 0);\
        ac01 = __builtin_amdgcn_mfma_i32_32x32x32_i8(av0, Wb, ac01, 0, 0, 0);\
        ac02 = __builtin_amdgcn_mfma_i32_32x32x32_i8(av0, Wc, ac02, 0, 0, 0);\
        ac03 = __builtin_amdgcn_mfma_i32_32x32x32_i8(av0, Wd, ac03, 0, 0, 0);\
        ac10 = __builtin_amdgcn_mfma_i32_32x32x32_i8(av1, Wa, ac10, 0, 0, 0);\
        ac11 = __builtin_amdgcn_mfma_i32_32x32x32_i8(av1, Wb, ac11, 0, 0, 0);\
        ac12 = __builtin_amdgcn_mfma_i32_32x32x32_i8(av1, Wc, ac12, 0, 0, 0);\
        ac13 = __builtin_amdgcn_mfma_i32_32x32x32_i8(av1, Wd, ac13, 0, 0, 0);\
        ISSUE(Wa, PA, OFFLIT); ISSUE(Wb, PB, OFFLIT);                        \
        ISSUE(Wc, PC, OFFLIT); ISSUE(Wd, PD, OFFLIT);                        \
    }

#pragma unroll 1
    for (int t = 0; t < 9; ++t) {
        const int kh = (t * 11) >> 5;                  // t/3 for t<9
        const int kw = t - kh * 3;
        const int cb0 = ((rb0 + kh) * 58 + w_0 + kw) * 64;
        const int f0  = (w_0 + kw + 2 * (rb0 + kh)) & 15;
        const int cb1 = ((rb1 + kh) * 58 + w_1 + kw) * 64;
        const int f1  = (w_1 + kw + 2 * (rb1 + kh)) & 15;

        // prefetch bases (stream-linear: byte = k*1024, k = t*8+c).
        // c=0,1 -> bA + {2048,3072}; c=2..5 -> bB(=bA+4096) + {0..3072};
        // c=6,7 -> bC(=next tap, clamped at t=8) + {0,1024} (dead, drained).
        const size_t tb = (size_t)t * 8192;
        const uint8_t* bA0 = sb0 + tb;  const uint8_t* bA1 = sb1 + tb;
        const uint8_t* bA2 = sb2 + tb;  const uint8_t* bA3 = sb3 + tb;
        const uint8_t* bB0 = bA0 + 4096; const uint8_t* bB1 = bA1 + 4096;
        const uint8_t* bB2 = bA2 + 4096; const uint8_t* bB3 = bA3 + 4096;
        const size_t nb = (t < 8) ? (tb + 8192) : tb;
        const uint8_t* bC0 = sb0 + nb;  const uint8_t* bC1 = sb1 + nb;
        const uint8_t* bC2 = sb2 + nb;  const uint8_t* bC3 = sb3 + nb;

        STEP(0, B00, B01, B02, B03, bA0, bA1, bA2, bA3, "2048")
        STEP(1, B10, B11, B12, B13, bA0, bA1, bA2, bA3, "3072")
        STEP(2, B00, B01, B02, B03, bB0, bB1, bB2, bB3, "0")
        STEP(3, B10, B11, B12, B13, bB0, bB1, bB2, bB3, "1024")
        STEP(4, B00, B01, B02, B03, bB0, bB1, bB2, bB3, "2048")
        STEP(5, B10, B11, B12, B13, bB0, bB1, bB2, bB3, "3072")
        STEP(6, B00, B01, B02, B03, bC0, bC1, bC2, bC3, "0")
        STEP(7, B10, B11, B12, B13, bC0, bC1, bC2, bC3, "1024")
    }
#undef STEP
#undef ISSUE

    // ---- drain: final prefetches still in flight target the window regs;
    // wait with the slots tied live so regalloc can't recycle them early.
    asm volatile("s_waitcnt vmcnt(0)"
        : "+v"(B00), "+v"(B01), "+v"(B02), "+v"(B03),
          "+v"(B10), "+v"(B11), "+v"(B12), "+v"(B13));

    // ---- epilogue: 4 rounds of 32 px through LDS transpose (obuf <= xt).
    __syncthreads();                      // all xt reads done
    float* obuf = (float*)xt;             // [32][257] floats = 32896 B
    float* ob = out + (size_t)b * (COUT * HW);

#pragma unroll 1
    for (int r = 0; r < 4; ++r) {
        if (mg == (r >> 1)) {
            const int rfr = r & 1;
#pragma unroll
            for (int reg = 0; reg < 16; ++reg) {
                const int row = (reg & 3) + ((reg >> 2) << 3) + (half << 2);
                if (r == 3 && row >= 16) continue;    // invalid px 112..127
                if (rfr == 0) {
                    obuf[row * 257 + cob]      = s0 * (float)ac00[reg];
                    obuf[row * 257 + cob + 32] = s1 * (float)ac01[reg];
                    obuf[row * 257 + cob + 64] = s2 * (float)ac02[reg];
                    obuf[row * 257 + cob + 96] = s3 * (float)ac03[reg];
                } else {
                    obuf[row * 257 + cob]      = s0 * (float)ac10[reg];
                    obuf[row * 257 + cob + 32] = s1 * (float)ac11[reg];
                    obuf[row * 257 + cob + 64] = s2 * (float)ac12[reg];
                    obuf[row * 257 + cob + 96] = s3 * (float)ac13[reg];
                }
            }
        }
        __syncthreads();
        const int k  = tid & 31;          // px within round
        const int cb = tid >> 5;          // 0..7
        const int pxb = p0 + r * 32;
        if (r < 3 || k < 16) {
#pragma unroll
            for (int j = 0; j < 32; ++j) {
                const int co = cb + 8 * j;
                ob[(size_t)co * HW + pxb + k] = obuf[k * 257 + co];
            }
        }
        __syncthreads();
    }
}

// ---------------------------------------------------------------------------
// C (fallback, ws too small for W8): exact R7 kernel — verified pass @140us.
// ---------------------------------------------------------------------------
__global__ __launch_bounds__(512, 2) void conv_mfma_kernel(
    const uint32_t* __restrict__ xbits, const unsigned short* __restrict__ wbT,
    const float* __restrict__ sa_g, float* __restrict__ out)
{
    __shared__ __align__(16) int xt[348 * 64];

    const int tid  = threadIdx.x;
    const int lane = tid & 63;
    const int half = lane >> 5;
    const int l31  = lane & 31;
    const int wid  = tid >> 6;
    const int mg   = wid >> 2;
    const int ng   = wid & 3;

    const int blk = blockIdx.x;
    const int b   = blk / 25;
    const int T   = blk - b * 25;
    const int p0  = T * 128;
    const bool full = (T < 24);
    const int mgE = full ? mg : 0;
    const int h0  = p0 / 56;

    {
        const uint32_t* xb = xbits + (size_t)b * (HW * WORDS);
        for (int u = tid; u < 348 * 32; u += 512) {
            const int cell = u >> 5, p = u & 31;
            const int row = cell / 58;
            const int col = cell - row * 58;
            const int hh = h0 - 1 + row, ww = col - 1;
            const bool ok = (hh >= 0) && (hh < Hdim) && (ww >= 0) && (ww < Wdim);
            uint32_t byteval = 0;
            if (ok)
                byteval = (xb[((hh * 56 + ww) << 3) + (p >> 2)] >> ((p & 3) * 8)) & 0xFFu;
            uint32_t d0 = nib2pm1(byteval & 15u);
            uint32_t d1 = nib2pm1(byteval >> 4);
            if (!ok) { d0 = 0u; d1 = 0u; }
            const int f   = (col + 2 * row) & 15;
            const int idx = cell * 64 + (((p >> 1) ^ f) << 2) + ((p & 1) << 1);
            *reinterpret_cast<uint2*>(&xt[idx]) = make_uint2(d0, d1);
        }
    }
    __syncthreads();

    const int px0 = p0 + mgE * 64 + l31;
    const int px1 = px0 + 32;
    const int h_0 = px0 / 56, w_0 = px0 - h_0 * 56;
    const int h_1 = px1 / 56, w_1 = px1 - h_1 * 56;
    const int rb0 = h_0 - h0, rb1 = h_1 - h0;

    const int co0 = ng * 64 + l31;
    const int co1 = co0 + 32;
    const float s0 = sa_g[co0], s1 = sa_g[co1];

    const unsigned short* wp0 = wbT + (((half << 8) + co0) << 3);
    const unsigned short* wp1 = wbT + (((half << 8) + co1) << 3);

    int16v a00 = {0,0,0,0,0,0,0,0,0,0,0,0,0,0,0,0};
    int16v a01 = {0,0,0,0,0,0,0,0,0,0,0,0,0,0,0,0};
    int16v a10 = {0,0,0,0,0,0,0,0,0,0,0,0,0,0,0,0};
    int16v a11 = {0,0,0,0,0,0,0,0,0,0,0,0,0,0,0,0};

    uint4 wb0 = *(const uint4*)wp0;
    uint4 wb1 = *(const uint4*)wp1;

#pragma unroll 1
    for (int t = 0; t < 9; ++t) {
        const int tn = (t < 8) ? (t + 1) : 8;
        const uint4 wb0n = *(const uint4*)(wp0 + tn * 4096);
        const uint4 wb1n = *(const uint4*)(wp1 + tn * 4096);

        const int kh = (t * 11) >> 5;
        const int kw = t - kh * 3;
        const int cb0 = ((rb0 + kh) * 58 + w_0 + kw) * 64;
        const int f0  = (w_0 + kw + 2 * (rb0 + kh)) & 15;
        const int cb1 = ((rb1 + kh) * 58 + w_1 + kw) * 64;
        const int f1  = (w_1 + kw + 2 * (rb1 + kh)) & 15;

#pragma unroll
        for (int c = 0; c < 8; ++c) {
            const int g0 = ((((c << 1) | half) ^ f0) << 2);
            const int g1 = ((((c << 1) | half) ^ f1) << 2);
            const int4v av0 = *(const int4v*)&xt[cb0 + g0];
            const int4v av1 = *(const int4v*)&xt[cb1 + g1];
            const int4v bv0 = expand_pm1(ext16(wb0, c));
            const int4v bv1 = expand_pm1(ext16(wb1, c));
            a00 = __builtin_amdgcn_mfma_i32_32x32x32_i8(av0, bv0, a00, 0, 0, 0);
            a01 = __builtin_amdgcn_mfma_i32_32x32x32_i8(av0, bv1, a01, 0, 0, 0);
            a10 = __builtin_amdgcn_mfma_i32_32x32x32_i8(av1, bv0, a10, 0, 0, 0);
            a11 = __builtin_amdgcn_mfma_i32_32x32x32_i8(av1, bv1, a11, 0, 0, 0);
        }
        wb0 = wb0n; wb1 = wb1n;
    }

    if (full || mg == 0) {
        float* ob = out + (size_t)b * (COUT * HW);
        const int pxb = p0 + mgE * 64;
#pragma unroll
        for (int reg = 0; reg < 16; ++reg) {
            const int row = (reg & 3) + ((reg >> 2) << 3) + (half << 2);
            ob[(size_t)co0 * HW + pxb + row]      = s0 * (float)a00[reg];
            ob[(size_t)co1 * HW + pxb + row]      = s1 * (float)a01[reg];
            ob[(size_t)co0 * HW + pxb + 32 + row] = s0 * (float)a10[reg];
            ob[(size_t)co1 * HW + pxb + 32 + row] = s1 * (float)a11[reg];
        }
    }
}

extern "C" void kernel_launch(void* const* d_in, const int* in_sizes, int n_in,
                              void* d_out, int out_size, void* d_ws, size_t ws_size,
                              hipStream_t stream) {
    const float* x     = (const float*)d_in[0];   // [32,256,56,56]
    const float* wts   = (const float*)d_in[1];   // [4,256,256,3,3]
    const float* RV    = (const float*)d_in[2];   // [5]
    const float* alpha = (const float*)d_in[3];   // [256,1,1]
    float* out = (float*)d_out;                   // [32,256,56,56]

    uint8_t* ws = (uint8_t*)d_ws;
    unsigned short* wbT = (unsigned short*)(ws + OFF_WBT);
    float*    sa    = (float*)   (ws + OFF_SA);
    uint32_t* xbits = (uint32_t*)(ws + OFF_XBITS);
    uint4*    w8    = (uint4*)   (ws + OFF_W8);

    const int has_w8 = (ws_size >= (size_t)WS_NEED) ? 1 : 0;

    prep_w_kernel<<<COUT, 256, 0, stream>>>(wts, RV, alpha, wbT, sa, w8, has_w8);
    pack_x_kernel<<<NPIX / 256, 256, 0, stream>>>(x, xbits);
    if (has_w8)
        conv_mfma_w8_kernel<<<BATCH * 28, 256, 0, stream>>>(
            xbits, (const uint8_t*)w8, sa, out);
    else
        conv_mfma_kernel<<<BATCH * 25, 512, 0, stream>>>(xbits, wbT, sa, out);
}

// Round 15
// 99.015 us; speedup vs baseline: 1.1660x; 1.1660x over previous
//
#include <hip/hip_runtime.h>
#include <stdint.h>

// Problem constants (fixed by reference setup_inputs)
#define CIN   256
#define COUT  256
#define Hdim  56
#define Wdim  56
#define HW    3136        // 56*56
#define BATCH 32
#define NPIX  100352      // 32*3136
#define KREP  589824      // 256*256*9, stride between weight replicas
#define TAPS  9
#define WORDS 8           // 8 x uint32 = 256 channel bits

// ws layout (bytes). First 3,286,016 B = R7-proven footprint (fallback path).
// W8 (expanded int8 weights, stream-contiguous layout) appended past it.
#define OFF_WBT   0         // 9*2*256*8 ushorts = 73728
#define OFF_SA    73728     // 256*4 = 1024
#define OFF_XBITS 74752     // 100352*8*4 = 3211264
#define OFF_W8    3286016   // 8 cg * 9 t * 8 c * 1024 B = 589824
#define WS_NEED   (OFF_W8 + 589824)

#define CGBYTES   73728     // W8 bytes per 32-co group (9*8*1024)

typedef int int4v  __attribute__((ext_vector_type(4)));
typedef int int16v __attribute__((ext_vector_type(16)));

// 4 sign bits -> 4 int8 lanes of {-1,+1}. Byte-borrow-proof:
// (0x81 - 2b) ^ 0x80 = {0x01, 0xFF} per byte, no cross-byte borrow.
__device__ __forceinline__ uint32_t nib2pm1(uint32_t n) {
    const uint32_t mask = (n * 0x204081u) & 0x01010101u;
    return (0x81818181u - (mask << 1)) ^ 0x80808080u;
}

__device__ __forceinline__ int4v expand_pm1(uint32_t us) {
    int4v r;
    r.x = (int)nib2pm1(us & 15u);
    r.y = (int)nib2pm1((us >> 4) & 15u);
    r.z = (int)nib2pm1((us >> 8) & 15u);
    r.w = (int)nib2pm1((us >> 12) & 15u);
    return r;
}

__device__ __forceinline__ uint32_t ext16(const uint4 v, int c) {
    uint32_t comp = (c < 4) ? ((c < 2) ? v.x : v.y) : ((c < 6) ? v.z : v.w);
    return (c & 1) ? (comp >> 16) : (comp & 0xFFFFu);
}

// ---------------------------------------------------------------------------
// P1: real_w = sum_k RV[k]*W[k]; sa[co] = mean|real_w| * alpha[co];
//     wbT bit-pack (fallback) and W8 expanded int8 B-fragments in the
//     stream-contiguous layout: byte = (co>>5)*73728 + (t*8+c)*1024
//     + g*512 + (co&31)*16. Verified R11/R13.
// ---------------------------------------------------------------------------
__global__ __launch_bounds__(256) void prep_w_kernel(
    const float* __restrict__ wts, const float* __restrict__ RV,
    const float* __restrict__ alpha, unsigned short* __restrict__ wbT,
    float* __restrict__ sa, uint4* __restrict__ w8, int do_w8)
{
    __shared__ uint32_t bits[TAPS * WORDS];   // bits[tap*8 + (ci>>5)]
    __shared__ float    red[256];

    const int co = blockIdx.x;
    const int t  = threadIdx.x;

    if (t < TAPS * WORDS) bits[t] = 0u;
    __syncthreads();

    const float r0 = RV[0], r1 = RV[1], r2 = RV[2], r3 = RV[3];
    const float* base = wts + (size_t)co * 2304;

    float acc = 0.f;
#pragma unroll
    for (int j = 0; j < 9; ++j) {
        const int e = j * 256 + t;              // e = ci*9 + tap
        const float w0 = base[e];
        const float w1 = base[e + KREP];
        const float w2 = base[e + 2 * KREP];
        const float w3 = base[e + 3 * KREP];
        const float rw = r0 * w0 + r1 * w1 + r2 * w2 + r3 * w3;
        acc += fabsf(rw);
        const int ci  = e / 9;
        const int tap = e - ci * 9;
        if (rw < 0.f)
            atomicOr(&bits[tap * WORDS + (ci >> 5)], 1u << (ci & 31));
    }
    red[t] = acc;
    __syncthreads();

    for (int s = 128; s > 0; s >>= 1) {
        if (t < s) red[t] += red[t + s];
        __syncthreads();
    }

    if (t == 0) sa[co] = (red[0] * (1.0f / 2304.0f)) * alpha[co];

    if (t < 144) {                       // wbT: (tap, g, c) — R7-verified
        const int tap = t >> 4;
        const int r   = t & 15;
        const int g   = r >> 3;
        const int c   = r & 7;
        const uint32_t v = (bits[tap * 8 + c] >> (g * 16)) & 0xFFFFu;
        wbT[(((tap * 2 + g) * 256 + co) << 3) + c] = (unsigned short)v;
    }
    if (do_w8 && t < 144) {              // W8 stream layout: (tap, q=2c+g)
        const int tap = t >> 4;
        const int q   = t & 15;
        const int c   = q >> 1;
        const int g   = q & 1;
        const uint32_t v = (bits[tap * 8 + c] >> (g * 16)) & 0xFFFFu;
        uint4 e;
        e.x = nib2pm1(v & 15u);
        e.y = nib2pm1((v >> 4) & 15u);
        e.z = nib2pm1((v >> 8) & 15u);
        e.w = nib2pm1((v >> 12) & 15u);
        // uint4 index: cg*4608 + (tap*8+c)*64 + g*32 + (co&31)
        w8[(co >> 5) * 4608 + (tap * 8 + c) * 64 + g * 32 + (co & 31)] = e;
    }
}

// ---------------------------------------------------------------------------
// P2: binarize+pack x (unpadded [B][56][56][8]) — unchanged, verified R1.
// ---------------------------------------------------------------------------
__global__ __launch_bounds__(256) void pack_x_kernel(
    const float* __restrict__ x, uint32_t* __restrict__ xbits)
{
    const int p  = blockIdx.x * 256 + threadIdx.x;   // pixel id < NPIX
    const int b  = p / HW;
    const int hw = p - b * HW;
    const float* xp = x + (size_t)b * CIN * HW + hw;

    uint32_t wv[WORDS];
#pragma unroll
    for (int j = 0; j < WORDS; ++j) {
        uint32_t m = 0;
#pragma unroll
        for (int bit = 0; bit < 32; ++bit) {
            const float v = xp[(size_t)(j * 32 + bit) * HW];
            m |= (__float_as_uint(v) >> 31) << bit;
        }
        wv[j] = m;
    }
    uint4* dst = (uint4*)(xbits + (size_t)p * WORDS);
    dst[0] = make_uint4(wv[0], wv[1], wv[2], wv[3]);
    dst[1] = make_uint4(wv[4], wv[5], wv[6], wv[7]);
}

// ---------------------------------------------------------------------------
// C (primary): implicit-GEMM XNOR conv, M=112 row-aligned tile,
// ZERO-B-REDUNDANCY waves: 8 waves = 8 co-groups (32 co each); each wave
// computes 4 M-frags x 1 N-frag, so every B byte is loaded once per block
// (590 KB vs R13's 1.15 MB -> per-CU B VMEM halves). 16 waves/CU kept
// (R14 lesson). Frag 3 rows >=16 are clamp-garbage (R9's proven pattern),
// skipped at store. B: single stream, 4-deep asm window, vmcnt(3), R13's
// proven NaN-safe drain. Staging/epilogue patterns = R9/R13-verified.
// ---------------------------------------------------------------------------
__global__ __launch_bounds__(512, 4) void conv_mfma_w8_kernel(
    const uint32_t* __restrict__ xbits, const uint8_t* __restrict__ w8,
    const float* __restrict__ sa_g, float* __restrict__ out)
{
    __shared__ __align__(16) int xt[232 * 64];  // 4 rows x 58 cols x 256B

    const int tid  = threadIdx.x;
    const int lane = tid & 63;
    const int half = lane >> 5;
    const int l31  = lane & 31;
    const int wid  = tid >> 6;       // 0..7 = co-group (N)

    const int blk = blockIdx.x;
    const int b   = blk / 28;
    const int T   = blk - b * 28;
    const int p0  = T * 112;
    const int h0  = 2 * T;           // first output row (aligned)

    // ---- stage + expand x tile (rows h0-1 .. h0+2, cols -1..56, pad = 0)
    {
        const uint32_t* xb = xbits + (size_t)b * (HW * WORDS);
        for (int u = tid; u < 232 * 32; u += 512) {   // b64 units
            const int cell = u >> 5, p = u & 31;
            const int row = cell / 58;                // 0..3
            const int col = cell - row * 58;          // 0..57
            const int hh = h0 - 1 + row, ww = col - 1;
            const bool ok = (hh >= 0) && (hh < Hdim) && (ww >= 0) && (ww < Wdim);
            uint32_t byteval = 0;
            if (ok)
                byteval = (xb[((hh * 56 + ww) << 3) + (p >> 2)] >> ((p & 3) * 8)) & 0xFFu;
            uint32_t d0 = nib2pm1(byteval & 15u);
            uint32_t d1 = nib2pm1(byteval >> 4);
            if (!ok) { d0 = 0u; d1 = 0u; }            // pad contributes 0
            const int f   = (col + 2 * row) & 15;
            const int idx = cell * 64 + (((p >> 1) ^ f) << 2) + ((p & 1) << 1);
            *reinterpret_cast<uint2*>(&xt[idx]) = make_uint2(d0, d1);
        }
    }
    __syncthreads();

    // ---- per-lane geometry: 4 M-frags (frag 3 lanes l31>=16 clamped;
    // their A rows are garbage; C rows >=16 of round 3 are skipped).
    const int q0 = p0 + l31;                   // frag 0
    const int q1 = q0 + 32;                    // frag 1
    const int q2 = q0 + 64;                    // frag 2
    int       q3 = q0 + 96;                    // frag 3 (clamp >= p0+112)
    if (q3 > p0 + 111) q3 = p0 + 111;
    const int rb0 = q0 / 56 - h0, w_0 = q0 - (rb0 + h0) * 56;
    const int rb1 = q1 / 56 - h0, w_1 = q1 - (rb1 + h0) * 56;
    const int rb2 = q2 / 56 - h0, w_2 = q2 - (rb2 + h0) * 56;
    const int rb3 = q3 / 56 - h0, w_3 = q3 - (rb3 + h0) * 56;

    const int cob = wid * 32 + l31;            // this wave's co for lane
    const float sA = sa_g[cob];

    // B stream base: lane*16 folds (half, co31); k*1024 walks the stream.
    const uint8_t* sb = w8 + (size_t)wid * CGBYTES + (lane << 4);

    int16v ac0 = {0,0,0,0,0,0,0,0,0,0,0,0,0,0,0,0};
    int16v ac1 = {0,0,0,0,0,0,0,0,0,0,0,0,0,0,0,0};
    int16v ac2 = {0,0,0,0,0,0,0,0,0,0,0,0,0,0,0,0};
    int16v ac3 = {0,0,0,0,0,0,0,0,0,0,0,0,0,0,0,0};

    int4v Bw[4];   // 4-deep rotating window, 4 loads in flight

#define ISSUE(DST, BASE, OFFLIT)                                             \
    asm volatile("global_load_dwordx4 %0, %1, off offset:" OFFLIT           \
                 : "=&v"(DST) : "v"(BASE))

    ISSUE(Bw[0], sb, "0");
    ISSUE(Bw[1], sb, "1024");
    ISSUE(Bw[2], sb, "2048");
    ISSUE(Bw[3], sb, "3072");

#define STEP(CC, PBASE, OFFLIT)                                              \
    {                                                                        \
        const int s_ = (CC) & 3;                                             \
        asm volatile("s_waitcnt vmcnt(3)" : "+v"(Bw[s_]));                   \
        __builtin_amdgcn_sched_barrier(0x3F7); /* MFMA may not hoist */      \
        const int4v bv = Bw[s_];                                             \
        const int gk = (((CC) << 1) | half);                                 \
        const int4v av0 = *(const int4v*)&xt[cb0 + ((gk ^ f0) << 2)];        \
        const int4v av1 = *(const int4v*)&xt[cb1 + ((gk ^ f1) << 2)];        \
        const int4v av2 = *(const int4v*)&xt[cb2 + ((gk ^ f2) << 2)];        \
        const int4v av3 = *(const int4v*)&xt[cb3 + ((gk ^ f3) << 2)];        \
        ac0 = __builtin_amdgcn_mfma_i32_32x32x32_i8(av0, bv, ac0, 0, 0, 0);  \
        ac1 = __builtin_amdgcn_mfma_i32_32x32x32_i8(av1, bv, ac1, 0, 0, 0);  \
        ac2 = __builtin_amdgcn_mfma_i32_32x32x32_i8(av2, bv, ac2, 0, 0, 0);  \
        ac3 = __builtin_amdgcn_mfma_i32_32x32x32_i8(av3, bv, ac3, 0, 0, 0);  \
        ISSUE(Bw[s_], PBASE, OFFLIT);                                        \
    }

#pragma unroll 1
    for (int t = 0; t < 9; ++t) {
        const int kh = (t * 11) >> 5;                  // t/3 for t<9
        const int kw = t - kh * 3;
        const int cb0 = ((rb0 + kh) * 58 + w_0 + kw) * 64;
        const int f0  = (w_0 + kw + 2 * (rb0 + kh)) & 15;
        const int cb1 = ((rb1 + kh) * 58 + w_1 + kw) * 64;
        const int f1  = (w_1 + kw + 2 * (rb1 + kh)) & 15;
        const int cb2 = ((rb2 + kh) * 58 + w_2 + kw) * 64;
        const int f2  = (w_2 + kw + 2 * (rb2 + kh)) & 15;
        const int cb3 = ((rb3 + kh) * 58 + w_3 + kw) * 64;
        const int f3  = (w_3 + kw + 2 * (rb3 + kh)) & 15;

        // prefetch: K-step (t*8+c)+4. c<4 -> this tap +4096; c>=4 -> next
        // tap (clamped at t=8: dead loads, drained below).
        const uint8_t* pT4 = sb + (size_t)t * 8192 + 4096;
        const int tn = (t < 8) ? (t + 1) : 8;
        const uint8_t* pN  = sb + (size_t)tn * 8192;

        STEP(0, pT4, "0")
        STEP(1, pT4, "1024")
        STEP(2, pT4, "2048")
        STEP(3, pT4, "3072")
        STEP(4, pN,  "0")
        STEP(5, pN,  "1024")
        STEP(6, pN,  "2048")
        STEP(7, pN,  "3072")
    }
#undef STEP
#undef ISSUE

    // ---- drain (R13-proven): final prefetches still in flight target the
    // window regs; wait with slots tied live so regalloc can't recycle them.
    asm volatile("s_waitcnt vmcnt(0)"
        : "+v"(Bw[0]), "+v"(Bw[1]), "+v"(Bw[2]), "+v"(Bw[3]));

    // ---- epilogue: 4 rounds of 32 px through LDS transpose (obuf <= xt).
    // Round r stores frag r; round 3 rows >=16 are clamp-garbage (skipped).
    __syncthreads();                      // all xt reads done
    float* obuf = (float*)xt;             // [32][257] floats = 32896 B
    float* ob = out + (size_t)b * (COUT * HW);

#define EPI(R, AC)                                                           \
    {                                                                        \
        _Pragma("unroll") for (int reg = 0; reg < 16; ++reg) {               \
            const int row = (reg & 3) + ((reg >> 2) << 3) + (half << 2);     \
            if ((R) == 3 && row >= 16) continue;   /* px 112..127 */         \
            obuf[row * 257 + cob] = sA * (float)(AC)[reg];                   \
        }                                                                    \
        __syncthreads();                                                     \
        const int k_  = tid & 31;          /* px within round */             \
        const int cq_ = tid >> 5;          /* 0..15 */                       \
        const int pxb_ = p0 + (R) * 32;                                      \
        if ((R) < 3 || k_ < 16) {                                            \
            _Pragma("unroll") for (int j = 0; j < 16; ++j) {                 \
                const int co_ = cq_ + 16 * j;                                \
                ob[(size_t)co_ * HW + pxb_ + k_] = obuf[k_ * 257 + co_];     \
            }                                                                \
        }                                                                    \
        __syncthreads();                                                     \
    }

    EPI(0, ac0)
    EPI(1, ac1)
    EPI(2, ac2)
    EPI(3, ac3)
#undef EPI
}

// ---------------------------------------------------------------------------
// C (fallback, ws too small for W8): exact R7 kernel — verified pass @140us.
// ---------------------------------------------------------------------------
__global__ __launch_bounds__(512, 2) void conv_mfma_kernel(
    const uint32_t* __restrict__ xbits, const unsigned short* __restrict__ wbT,
    const float* __restrict__ sa_g, float* __restrict__ out)
{
    __shared__ __align__(16) int xt[348 * 64];

    const int tid  = threadIdx.x;
    const int lane = tid & 63;
    const int half = lane >> 5;
    const int l31  = lane & 31;
    const int wid  = tid >> 6;
    const int mg   = wid >> 2;
    const int ng   = wid & 3;

    const int blk = blockIdx.x;
    const int b   = blk / 25;
    const int T   = blk - b * 25;
    const int p0  = T * 128;
    const bool full = (T < 24);
    const int mgE = full ? mg : 0;
    const int h0  = p0 / 56;

    {
        const uint32_t* xb = xbits + (size_t)b * (HW * WORDS);
        for (int u = tid; u < 348 * 32; u += 512) {
            const int cell = u >> 5, p = u & 31;
            const int row = cell / 58;
            const int col = cell - row * 58;
            const int hh = h0 - 1 + row, ww = col - 1;
            const bool ok = (hh >= 0) && (hh < Hdim) && (ww >= 0) && (ww < Wdim);
            uint32_t byteval = 0;
            if (ok)
                byteval = (xb[((hh * 56 + ww) << 3) + (p >> 2)] >> ((p & 3) * 8)) & 0xFFu;
            uint32_t d0 = nib2pm1(byteval & 15u);
            uint32_t d1 = nib2pm1(byteval >> 4);
            if (!ok) { d0 = 0u; d1 = 0u; }
            const int f   = (col + 2 * row) & 15;
            const int idx = cell * 64 + (((p >> 1) ^ f) << 2) + ((p & 1) << 1);
            *reinterpret_cast<uint2*>(&xt[idx]) = make_uint2(d0, d1);
        }
    }
    __syncthreads();

    const int px0 = p0 + mgE * 64 + l31;
    const int px1 = px0 + 32;
    const int h_0 = px0 / 56, w_0 = px0 - h_0 * 56;
    const int h_1 = px1 / 56, w_1 = px1 - h_1 * 56;
    const int rb0 = h_0 - h0, rb1 = h_1 - h0;

    const int co0 = ng * 64 + l31;
    const int co1 = co0 + 32;
    const float s0 = sa_g[co0], s1 = sa_g[co1];

    const unsigned short* wp0 = wbT + (((half << 8) + co0) << 3);
    const unsigned short* wp1 = wbT + (((half << 8) + co1) << 3);

    int16v a00 = {0,0,0,0,0,0,0,0,0,0,0,0,0,0,0,0};
    int16v a01 = {0,0,0,0,0,0,0,0,0,0,0,0,0,0,0,0};
    int16v a10 = {0,0,0,0,0,0,0,0,0,0,0,0,0,0,0,0};
    int16v a11 = {0,0,0,0,0,0,0,0,0,0,0,0,0,0,0,0};

    uint4 wb0 = *(const uint4*)wp0;
    uint4 wb1 = *(const uint4*)wp1;

#pragma unroll 1
    for (int t = 0; t < 9; ++t) {
        const int tn = (t < 8) ? (t + 1) : 8;
        const uint4 wb0n = *(const uint4*)(wp0 + tn * 4096);
        const uint4 wb1n = *(const uint4*)(wp1 + tn * 4096);

        const int kh = (t * 11) >> 5;
        const int kw = t - kh * 3;
        const int cb0 = ((rb0 + kh) * 58 + w_0 + kw) * 64;
        const int f0  = (w_0 + kw + 2 * (rb0 + kh)) & 15;
        const int cb1 = ((rb1 + kh) * 58 + w_1 + kw) * 64;
        const int f1  = (w_1 + kw + 2 * (rb1 + kh)) & 15;

#pragma unroll
        for (int c = 0; c < 8; ++c) {
            const int g0 = ((((c << 1) | half) ^ f0) << 2);
            const int g1 = ((((c << 1) | half) ^ f1) << 2);
            const int4v av0 = *(const int4v*)&xt[cb0 + g0];
            const int4v av1 = *(const int4v*)&xt[cb1 + g1];
            const int4v bv0 = expand_pm1(ext16(wb0, c));
            const int4v bv1 = expand_pm1(ext16(wb1, c));
            a00 = __builtin_amdgcn_mfma_i32_32x32x32_i8(av0, bv0, a00, 0, 0, 0);
            a01 = __builtin_amdgcn_mfma_i32_32x32x32_i8(av0, bv1, a01, 0, 0, 0);
            a10 = __builtin_amdgcn_mfma_i32_32x32x32_i8(av1, bv0, a10, 0, 0, 0);
            a11 = __builtin_amdgcn_mfma_i32_32x32x32_i8(av1, bv1, a11, 0, 0, 0);
        }
        wb0 = wb0n; wb1 = wb1n;
    }

    if (full || mg == 0) {
        float* ob = out + (size_t)b * (COUT * HW);
        const int pxb = p0 + mgE * 64;
#pragma unroll
        for (int reg = 0; reg < 16; ++reg) {
            const int row = (reg & 3) + ((reg >> 2) << 3) + (half << 2);
            ob[(size_t)co0 * HW + pxb + row]      = s0 * (float)a00[reg];
            ob[(size_t)co1 * HW + pxb + row]      = s1 * (float)a01[reg];
            ob[(size_t)co0 * HW + pxb + 32 + row] = s0 * (float)a10[reg];
            ob[(size_t)co1 * HW + pxb + 32 + row] = s1 * (float)a11[reg];
        }
    }
}

extern "C" void kernel_launch(void* const* d_in, const int* in_sizes, int n_in,
                              void* d_out, int out_size, void* d_ws, size_t ws_size,
                              hipStream_t stream) {
    const float* x     = (const float*)d_in[0];   // [32,256,56,56]
    const float* wts   = (const float*)d_in[1];   // [4,256,256,3,3]
    const float* RV    = (const float*)d_in[2];   // [5]
    const float* alpha = (const float*)d_in[3];   // [256,1,1]
    float* out = (float*)d_out;                   // [32,256,56,56]

    uint8_t* ws = (uint8_t*)d_ws;
    unsigned short* wbT = (unsigned short*)(ws + OFF_WBT);
    float*    sa    = (float*)   (ws + OFF_SA);
    uint32_t* xbits = (uint32_t*)(ws + OFF_XBITS);
    uint4*    w8    = (uint4*)   (ws + OFF_W8);

    const int has_w8 = (ws_size >= (size_t)WS_NEED) ? 1 : 0;

    prep_w_kernel<<<COUT, 256, 0, stream>>>(wts, RV, alpha, wbT, sa, w8, has_w8);
    pack_x_kernel<<<NPIX / 256, 256, 0, stream>>>(x, xbits);
    if (has_w8)
        conv_mfma_w8_kernel<<<BATCH * 28, 512, 0, stream>>>(
            xbits, (const uint8_t*)w8, sa, out);
    else
        conv_mfma_kernel<<<BATCH * 25, 512, 0, stream>>>(xbits, wbT, sa, out);
}

// Round 16
// 71.421 us; speedup vs baseline: 1.6164x; 1.3864x over previous
//
#include <hip/hip_runtime.h>
#include <stdint.h>

// Problem constants (fixed by reference setup_inputs)
#define CIN   256
#define COUT  256
#define Hdim  56
#define Wdim  56
#define HW    3136        // 56*56
#define BATCH 32
#define NPIX  100352      // 32*3136
#define KREP  589824      // 256*256*9, stride between weight replicas
#define TAPS  9
#define WORDS 8           // 8 x uint32 = 256 channel bits

// ws layout (bytes). First 3,286,016 B = R7-proven footprint (fallback path).
// W4 (fp4-expanded weights, stream layout, 294912 B) reuses the proven W8
// slot (589824 B) — total ws footprint unchanged from R13/R15.
#define OFF_WBT   0         // 9*2*256*8 ushorts = 73728
#define OFF_SA    73728     // 256*4 = 1024
#define OFF_XBITS 74752     // 100352*8*4 = 3211264
#define OFF_W8    3286016   // W4: 8 cg * 36 s * 1024 B = 294912 (<= 589824)
#define WS_NEED   (OFF_W8 + 589824)

#define CG4BYTES  36864     // W4 bytes per 32-co group (36 steps * 1024)

typedef int   int4v  __attribute__((ext_vector_type(4)));
typedef int   int8v  __attribute__((ext_vector_type(8)));
typedef int   int16v __attribute__((ext_vector_type(16)));
typedef float f32x16 __attribute__((ext_vector_type(16)));

// 4 sign bits -> 4 int8 lanes of {-1,+1} (i8 fallback path). Borrow-proof.
__device__ __forceinline__ uint32_t nib2pm1(uint32_t n) {
    const uint32_t mask = (n * 0x204081u) & 0x01010101u;
    return (0x81818181u - (mask << 1)) ^ 0x80808080u;
}

__device__ __forceinline__ int4v expand_pm1(uint32_t us) {
    int4v r;
    r.x = (int)nib2pm1(us & 15u);
    r.y = (int)nib2pm1((us >> 4) & 15u);
    r.z = (int)nib2pm1((us >> 8) & 15u);
    r.w = (int)nib2pm1((us >> 12) & 15u);
    return r;
}

__device__ __forceinline__ uint32_t ext16(const uint4 v, int c) {
    uint32_t comp = (c < 4) ? ((c < 2) ? v.x : v.y) : ((c < 6) ? v.z : v.w);
    return (c & 1) ? (comp >> 16) : (comp & 0xFFFFu);
}

// 8 sign bits -> 8 fp4 e2m1 nibbles of {+1,-1}: nibble = 0x2 | (sign<<3).
__device__ __forceinline__ uint32_t enc8(uint32_t m) {
    uint32_t s = (m & 0x01u);
    s |= (m & 0x02u) << 3;
    s |= (m & 0x04u) << 6;
    s |= (m & 0x08u) << 9;
    s |= (m & 0x10u) << 12;
    s |= (m & 0x20u) << 15;
    s |= (m & 0x40u) << 18;
    s |= (m & 0x80u) << 21;
    return 0x22222222u | (s << 3);
}

// ---------------------------------------------------------------------------
// P1: real_w = sum_k RV[k]*W[k]; sa[co] = mean|real_w| * alpha[co];
//     wbT bit-pack (fallback, R7-verified) and W4 fp4 B-fragments in the
//     stream layout: uint4 idx = cg*2304 + s*64 + lane, s = tap*4 + c,
//     lane = g*32 + (co&31); content = fp4 nibbles (ci-linear) for
//     ci = c*64 + g*32 + 0..31. Same (lane-half, nibble)->k map as the
//     conv's A fragments -> permutation-cancellation (R7 principle).
// ---------------------------------------------------------------------------
__global__ __launch_bounds__(256) void prep_w_kernel(
    const float* __restrict__ wts, const float* __restrict__ RV,
    const float* __restrict__ alpha, unsigned short* __restrict__ wbT,
    float* __restrict__ sa, uint4* __restrict__ w4, int do_w4)
{
    __shared__ uint32_t bits[TAPS * WORDS];   // bits[tap*8 + (ci>>5)]
    __shared__ float    red[256];

    const int co = blockIdx.x;
    const int t  = threadIdx.x;

    if (t < TAPS * WORDS) bits[t] = 0u;
    __syncthreads();

    const float r0 = RV[0], r1 = RV[1], r2 = RV[2], r3 = RV[3];
    const float* base = wts + (size_t)co * 2304;

    float acc = 0.f;
#pragma unroll
    for (int j = 0; j < 9; ++j) {
        const int e = j * 256 + t;              // e = ci*9 + tap
        const float w0 = base[e];
        const float w1 = base[e + KREP];
        const float w2 = base[e + 2 * KREP];
        const float w3 = base[e + 3 * KREP];
        const float rw = r0 * w0 + r1 * w1 + r2 * w2 + r3 * w3;
        acc += fabsf(rw);
        const int ci  = e / 9;
        const int tap = e - ci * 9;
        if (rw < 0.f)
            atomicOr(&bits[tap * WORDS + (ci >> 5)], 1u << (ci & 31));
    }
    red[t] = acc;
    __syncthreads();

    for (int s = 128; s > 0; s >>= 1) {
        if (t < s) red[t] += red[t + s];
        __syncthreads();
    }

    if (t == 0) sa[co] = (red[0] * (1.0f / 2304.0f)) * alpha[co];

    if (t < 144) {                       // wbT: (tap, g, c) — R7-verified
        const int tap = t >> 4;
        const int r   = t & 15;
        const int g   = r >> 3;
        const int c   = r & 7;
        const uint32_t v = (bits[tap * 8 + c] >> (g * 16)) & 0xFFFFu;
        wbT[(((tap * 2 + g) * 256 + co) << 3) + c] = (unsigned short)v;
    }
    if (do_w4 && t < 72) {               // W4: (tap, c, g)
        const int tap = t >> 3;
        const int r   = t & 7;
        const int c   = r >> 1;          // 64-ch k-step within tap
        const int g   = r & 1;           // lane-half (ci 32-group)
        const uint32_t v32 = bits[tap * 8 + c * 2 + g];   // ci c*64+g*32 ..+31
        uint4 e;
        e.x = enc8(v32 & 0xFFu);
        e.y = enc8((v32 >> 8) & 0xFFu);
        e.z = enc8((v32 >> 16) & 0xFFu);
        e.w = enc8(v32 >> 24);
        const int lane = g * 32 + (co & 31);
        w4[(co >> 5) * 2304 + (tap * 4 + c) * 64 + lane] = e;
    }
}

// ---------------------------------------------------------------------------
// P2: binarize+pack x (unpadded [B][56][56][8]) — unchanged, verified R1.
// ---------------------------------------------------------------------------
__global__ __launch_bounds__(256) void pack_x_kernel(
    const float* __restrict__ x, uint32_t* __restrict__ xbits)
{
    const int p  = blockIdx.x * 256 + threadIdx.x;   // pixel id < NPIX
    const int b  = p / HW;
    const int hw = p - b * HW;
    const float* xp = x + (size_t)b * CIN * HW + hw;

    uint32_t wv[WORDS];
#pragma unroll
    for (int j = 0; j < WORDS; ++j) {
        uint32_t m = 0;
#pragma unroll
        for (int bit = 0; bit < 32; ++bit) {
            const float v = xp[(size_t)(j * 32 + bit) * HW];
            m |= (__float_as_uint(v) >> 31) << bit;
        }
        wv[j] = m;
    }
    uint4* dst = (uint4*)(xbits + (size_t)p * WORDS);
    dst[0] = make_uint4(wv[0], wv[1], wv[2], wv[3]);
    dst[1] = make_uint4(wv[4], wv[5], wv[6], wv[7]);
}

// ---------------------------------------------------------------------------
// C (primary): implicit-GEMM XNOR conv on the MX-FP4 matrix pipe.
// Same geometry as R15 (M=112 tile, 8 waves x (4M x 1N), zero B redundancy,
// 4-deep asm B window) but K=64/instr: 36 k-steps, MFMA floor ~15.5us,
// A-LDS bytes and B bytes halve. fp4 {+1,-1}, pad=0 (all exact); scales=1.0
// (E8M0 0x7F). A/B built with the identical (lane-half,nibble)->k map.
// LDS: xt 29696 B; obuf 32896 B overlays -> block LDS 32896.
// ---------------------------------------------------------------------------
__global__ __launch_bounds__(512, 4) void conv_mfma_w4_kernel(
    const uint32_t* __restrict__ xbits, const uint8_t* __restrict__ w4,
    const float* __restrict__ sa_g, float* __restrict__ out)
{
    __shared__ __align__(16) int xt[8224];   // max(29696, 32896) bytes

    const int tid  = threadIdx.x;
    const int lane = tid & 63;
    const int half = lane >> 5;
    const int l31  = lane & 31;
    const int wid  = tid >> 6;       // 0..7 = co-group (N)

    const int blk = blockIdx.x;
    const int b   = blk / 28;
    const int T   = blk - b * 28;
    const int p0  = T * 112;
    const int h0  = 2 * T;           // first output row (aligned)

    // ---- stage + expand x tile to fp4 (rows h0-1..h0+2, cols -1..56, pad=0)
    // cell = row*58+col holds 128 B (256 fp4); chunk q (16B) swizzled by
    // f = (col+2*row)&7; unit = 8 B (16 nibbles, ci = p*16 ..+15).
    {
        const uint32_t* xb = xbits + (size_t)b * (HW * WORDS);
        char* xtc = (char*)xt;
        for (int u = tid; u < 232 * 16; u += 512) {
            const int cell = u >> 4, p = u & 15;
            const int row = cell / 58;                // 0..3
            const int col = cell - row * 58;          // 0..57
            const int hh = h0 - 1 + row, ww = col - 1;
            const bool ok = (hh >= 0) && (hh < Hdim) && (ww >= 0) && (ww < Wdim);
            uint32_t m16 = 0;
            if (ok)
                m16 = (xb[((hh * 56 + ww) << 3) + (p >> 1)] >> ((p & 1) * 16)) & 0xFFFFu;
            uint2 d;
            d.x = enc8(m16 & 0xFFu);
            d.y = enc8(m16 >> 8);
            if (!ok) { d.x = 0u; d.y = 0u; }          // fp4 zero: pad = 0
            const int f = (col + 2 * row) & 7;
            const int byteoff = cell * 128 + (((p >> 1) ^ f) << 4) + ((p & 1) << 3);
            *reinterpret_cast<uint2*>(xtc + byteoff) = d;
        }
    }
    __syncthreads();

    // ---- per-lane geometry (R15-verified)
    const int q0 = p0 + l31;                   // frag 0
    const int q1 = q0 + 32;                    // frag 1
    const int q2 = q0 + 64;                    // frag 2
    int       q3 = q0 + 96;                    // frag 3 (clamp >= p0+112)
    if (q3 > p0 + 111) q3 = p0 + 111;
    const int rb0 = q0 / 56 - h0, w_0 = q0 - (rb0 + h0) * 56;
    const int rb1 = q1 / 56 - h0, w_1 = q1 - (rb1 + h0) * 56;
    const int rb2 = q2 / 56 - h0, w_2 = q2 - (rb2 + h0) * 56;
    const int rb3 = q3 / 56 - h0, w_3 = q3 - (rb3 + h0) * 56;

    const int cob = wid * 32 + l31;            // this wave's co for lane
    const float sA = sa_g[cob];

    // B stream base: lane*16 folds (half, co31); s*1024 walks the stream.
    const uint8_t* sb = w4 + (size_t)wid * CG4BYTES + (lane << 4);

    f32x16 ac0 = {0.f}; f32x16 ac1 = {0.f};
    f32x16 ac2 = {0.f}; f32x16 ac3 = {0.f};

    int4v Bw[4];   // 4-deep rotating window (one tap ahead)

#define ISSUE(DST, BASE, OFFLIT)                                             \
    asm volatile("global_load_dwordx4 %0, %1, off offset:" OFFLIT           \
                 : "=&v"(DST) : "v"(BASE))

    ISSUE(Bw[0], sb, "0");
    ISSUE(Bw[1], sb, "1024");
    ISSUE(Bw[2], sb, "2048");
    ISSUE(Bw[3], sb, "3072");

    const char* xtc = (const char*)xt;

#define STEP(CC, PBASE, OFFLIT)                                              \
    {                                                                        \
        asm volatile("s_waitcnt vmcnt(3)" : "+v"(Bw[CC]));                   \
        __builtin_amdgcn_sched_barrier(0x3F7); /* MFMA may not hoist */      \
        const int4v bv = Bw[CC];                                             \
        const int8v b8 = {bv.x, bv.y, bv.z, bv.w, 0, 0, 0, 0};               \
        const int gk = (((CC) << 1) | half);                                 \
        const int4v a0_ = *(const int4v*)(xtc + cb0 + ((gk ^ f0) << 4));     \
        const int4v a1_ = *(const int4v*)(xtc + cb1 + ((gk ^ f1) << 4));     \
        const int4v a2_ = *(const int4v*)(xtc + cb2 + ((gk ^ f2) << 4));     \
        const int4v a3_ = *(const int4v*)(xtc + cb3 + ((gk ^ f3) << 4));     \
        const int8v a80 = {a0_.x, a0_.y, a0_.z, a0_.w, 0, 0, 0, 0};          \
        const int8v a81 = {a1_.x, a1_.y, a1_.z, a1_.w, 0, 0, 0, 0};          \
        const int8v a82 = {a2_.x, a2_.y, a2_.z, a2_.w, 0, 0, 0, 0};          \
        const int8v a83 = {a3_.x, a3_.y, a3_.z, a3_.w, 0, 0, 0, 0};          \
        ac0 = __builtin_amdgcn_mfma_scale_f32_32x32x64_f8f6f4(               \
            a80, b8, ac0, 4, 4, 0, 0x7F7F7F7F, 0, 0x7F7F7F7F);               \
        ac1 = __builtin_amdgcn_mfma_scale_f32_32x32x64_f8f6f4(               \
            a81, b8, ac1, 4, 4, 0, 0x7F7F7F7F, 0, 0x7F7F7F7F);               \
        ac2 = __builtin_amdgcn_mfma_scale_f32_32x32x64_f8f6f4(               \
            a82, b8, ac2, 4, 4, 0, 0x7F7F7F7F, 0, 0x7F7F7F7F);               \
        ac3 = __builtin_amdgcn_mfma_scale_f32_32x32x64_f8f6f4(               \
            a83, b8, ac3, 4, 4, 0, 0x7F7F7F7F, 0, 0x7F7F7F7F);               \
        ISSUE(Bw[CC], PBASE, OFFLIT);                                        \
    }

#pragma unroll 1
    for (int t = 0; t < 9; ++t) {
        const int kh = (t * 11) >> 5;                  // t/3 for t<9
        const int kw = t - kh * 3;
        const int cb0 = ((rb0 + kh) * 58 + w_0 + kw) * 128;
        const int f0  = (w_0 + kw + 2 * (rb0 + kh)) & 7;
        const int cb1 = ((rb1 + kh) * 58 + w_1 + kw) * 128;
        const int f1  = (w_1 + kw + 2 * (rb1 + kh)) & 7;
        const int cb2 = ((rb2 + kh) * 58 + w_2 + kw) * 128;
        const int f2  = (w_2 + kw + 2 * (rb2 + kh)) & 7;
        const int cb3 = ((rb3 + kh) * 58 + w_3 + kw) * 128;
        const int f3  = (w_3 + kw + 2 * (rb3 + kh)) & 7;

        // prefetch: step (t*4+c)+4 = tap t+1, same c (clamped at t=8:
        // dead reloads, drained below).
        const int tn = (t < 8) ? (t + 1) : 8;
        const uint8_t* pN = sb + (size_t)tn * 4096;

        STEP(0, pN, "0")
        STEP(1, pN, "1024")
        STEP(2, pN, "2048")
        STEP(3, pN, "3072")
    }
#undef STEP
#undef ISSUE

    // ---- drain (R13-proven): final prefetches still target window regs.
    asm volatile("s_waitcnt vmcnt(0)"
        : "+v"(Bw[0]), "+v"(Bw[1]), "+v"(Bw[2]), "+v"(Bw[3]));

    // ---- epilogue: 4 rounds of 32 px through LDS transpose (obuf <= xt).
    __syncthreads();                      // all xt reads done
    float* obuf = (float*)xt;             // [32][257] floats = 32896 B
    float* ob = out + (size_t)b * (COUT * HW);

#define EPI(R, AC)                                                           \
    {                                                                        \
        _Pragma("unroll") for (int reg = 0; reg < 16; ++reg) {               \
            const int row = (reg & 3) + ((reg >> 2) << 3) + (half << 2);     \
            if ((R) == 3 && row >= 16) continue;   /* px 112..127 */         \
            obuf[row * 257 + cob] = sA * (AC)[reg];                          \
        }                                                                    \
        __syncthreads();                                                     \
        const int k_  = tid & 31;          /* px within round */             \
        const int cq_ = tid >> 5;          /* 0..15 */                       \
        const int pxb_ = p0 + (R) * 32;                                      \
        if ((R) < 3 || k_ < 16) {                                            \
            _Pragma("unroll") for (int j = 0; j < 16; ++j) {                 \
                const int co_ = cq_ + 16 * j;                                \
                ob[(size_t)co_ * HW + pxb_ + k_] = obuf[k_ * 257 + co_];     \
            }                                                                \
        }                                                                    \
        __syncthreads();                                                     \
    }

    EPI(0, ac0)
    EPI(1, ac1)
    EPI(2, ac2)
    EPI(3, ac3)
#undef EPI
}

// ---------------------------------------------------------------------------
// C (fallback, ws too small): exact R7 i8 kernel — verified pass @140us.
// ---------------------------------------------------------------------------
__global__ __launch_bounds__(512, 2) void conv_mfma_kernel(
    const uint32_t* __restrict__ xbits, const unsigned short* __restrict__ wbT,
    const float* __restrict__ sa_g, float* __restrict__ out)
{
    __shared__ __align__(16) int xt[348 * 64];

    const int tid  = threadIdx.x;
    const int lane = tid & 63;
    const int half = lane >> 5;
    const int l31  = lane & 31;
    const int wid  = tid >> 6;
    const int mg   = wid >> 2;
    const int ng   = wid & 3;

    const int blk = blockIdx.x;
    const int b   = blk / 25;
    const int T   = blk - b * 25;
    const int p0  = T * 128;
    const bool full = (T < 24);
    const int mgE = full ? mg : 0;
    const int h0  = p0 / 56;

    {
        const uint32_t* xb = xbits + (size_t)b * (HW * WORDS);
        for (int u = tid; u < 348 * 32; u += 512) {
            const int cell = u >> 5, p = u & 31;
            const int row = cell / 58;
            const int col = cell - row * 58;
            const int hh = h0 - 1 + row, ww = col - 1;
            const bool ok = (hh >= 0) && (hh < Hdim) && (ww >= 0) && (ww < Wdim);
            uint32_t byteval = 0;
            if (ok)
                byteval = (xb[((hh * 56 + ww) << 3) + (p >> 2)] >> ((p & 3) * 8)) & 0xFFu;
            uint32_t d0 = nib2pm1(byteval & 15u);
            uint32_t d1 = nib2pm1(byteval >> 4);
            if (!ok) { d0 = 0u; d1 = 0u; }
            const int f   = (col + 2 * row) & 15;
            const int idx = cell * 64 + (((p >> 1) ^ f) << 2) + ((p & 1) << 1);
            *reinterpret_cast<uint2*>(&xt[idx]) = make_uint2(d0, d1);
        }
    }
    __syncthreads();

    const int px0 = p0 + mgE * 64 + l31;
    const int px1 = px0 + 32;
    const int h_0 = px0 / 56, w_0 = px0 - h_0 * 56;
    const int h_1 = px1 / 56, w_1 = px1 - h_1 * 56;
    const int rb0 = h_0 - h0, rb1 = h_1 - h0;

    const int co0 = ng * 64 + l31;
    const int co1 = co0 + 32;
    const float s0 = sa_g[co0], s1 = sa_g[co1];

    const unsigned short* wp0 = wbT + (((half << 8) + co0) << 3);
    const unsigned short* wp1 = wbT + (((half << 8) + co1) << 3);

    int16v a00 = {0,0,0,0,0,0,0,0,0,0,0,0,0,0,0,0};
    int16v a01 = {0,0,0,0,0,0,0,0,0,0,0,0,0,0,0,0};
    int16v a10 = {0,0,0,0,0,0,0,0,0,0,0,0,0,0,0,0};
    int16v a11 = {0,0,0,0,0,0,0,0,0,0,0,0,0,0,0,0};

    uint4 wb0 = *(const uint4*)wp0;
    uint4 wb1 = *(const uint4*)wp1;

#pragma unroll 1
    for (int t = 0; t < 9; ++t) {
        const int tn = (t < 8) ? (t + 1) : 8;
        const uint4 wb0n = *(const uint4*)(wp0 + tn * 4096);
        const uint4 wb1n = *(const uint4*)(wp1 + tn * 4096);

        const int kh = (t * 11) >> 5;
        const int kw = t - kh * 3;
        const int cb0 = ((rb0 + kh) * 58 + w_0 + kw) * 64;
        const int f0  = (w_0 + kw + 2 * (rb0 + kh)) & 15;
        const int cb1 = ((rb1 + kh) * 58 + w_1 + kw) * 64;
        const int f1  = (w_1 + kw + 2 * (rb1 + kh)) & 15;

#pragma unroll
        for (int c = 0; c < 8; ++c) {
            const int g0 = ((((c << 1) | half) ^ f0) << 2);
            const int g1 = ((((c << 1) | half) ^ f1) << 2);
            const int4v av0 = *(const int4v*)&xt[cb0 + g0];
            const int4v av1 = *(const int4v*)&xt[cb1 + g1];
            const int4v bv0 = expand_pm1(ext16(wb0, c));
            const int4v bv1 = expand_pm1(ext16(wb1, c));
            a00 = __builtin_amdgcn_mfma_i32_32x32x32_i8(av0, bv0, a00, 0, 0, 0);
            a01 = __builtin_amdgcn_mfma_i32_32x32x32_i8(av0, bv1, a01, 0, 0, 0);
            a10 = __builtin_amdgcn_mfma_i32_32x32x32_i8(av1, bv0, a10, 0, 0, 0);
            a11 = __builtin_amdgcn_mfma_i32_32x32x32_i8(av1, bv1, a11, 0, 0, 0);
        }
        wb0 = wb0n; wb1 = wb1n;
    }

    if (full || mg == 0) {
        float* ob = out + (size_t)b * (COUT * HW);
        const int pxb = p0 + mgE * 64;
#pragma unroll
        for (int reg = 0; reg < 16; ++reg) {
            const int row = (reg & 3) + ((reg >> 2) << 3) + (half << 2);
            ob[(size_t)co0 * HW + pxb + row]      = s0 * (float)a00[reg];
            ob[(size_t)co1 * HW + pxb + row]      = s1 * (float)a01[reg];
            ob[(size_t)co0 * HW + pxb + 32 + row] = s0 * (float)a10[reg];
            ob[(size_t)co1 * HW + pxb + 32 + row] = s1 * (float)a11[reg];
        }
    }
}

extern "C" void kernel_launch(void* const* d_in, const int* in_sizes, int n_in,
                              void* d_out, int out_size, void* d_ws, size_t ws_size,
                              hipStream_t stream) {
    const float* x     = (const float*)d_in[0];   // [32,256,56,56]
    const float* wts   = (const float*)d_in[1];   // [4,256,256,3,3]
    const float* RV    = (const float*)d_in[2];   // [5]
    const float* alpha = (const float*)d_in[3];   // [256,1,1]
    float* out = (float*)d_out;                   // [32,256,56,56]

    uint8_t* ws = (uint8_t*)d_ws;
    unsigned short* wbT = (unsigned short*)(ws + OFF_WBT);
    float*    sa    = (float*)   (ws + OFF_SA);
    uint32_t* xbits = (uint32_t*)(ws + OFF_XBITS);
    uint4*    w4    = (uint4*)   (ws + OFF_W8);

    const int has_w4 = (ws_size >= (size_t)WS_NEED) ? 1 : 0;

    prep_w_kernel<<<COUT, 256, 0, stream>>>(wts, RV, alpha, wbT, sa, w4, has_w4);
    pack_x_kernel<<<NPIX / 256, 256, 0, stream>>>(x, xbits);
    if (has_w4)
        conv_mfma_w4_kernel<<<BATCH * 28, 512, 0, stream>>>(
            xbits, (const uint8_t*)w4, sa, out);
    else
        conv_mfma_kernel<<<BATCH * 25, 512, 0, stream>>>(xbits, wbT, sa, out);
}